// Round 1
// baseline (214.463 us; speedup 1.0000x reference)
//
#include <hip/hip_runtime.h>
#include <math.h>

// Problem constants
#define NB 8      // batch rows actually needed (channel 0 only!)
#define LL 512
#define DD 128
#define PP 96
#define QQ 3

struct BandW {
  const float* cheb[4];
  const float* w1[4];
  const float* b1[4];
  const float* w2[4];
  const float* b2[4];
};

// db4 low-pass (pywt) — all filters derived from this at compile time.
constexpr float W_LO[8] = {
  -0.010597401784997278f, 0.032883011666982945f, 0.030841381835986965f,
  -0.18703481171888114f, -0.02798376941698385f, 0.6308807679295904f,
  0.7148465705525415f, 0.23037781330885523f
};

__device__ __forceinline__ float gelu_exact(float x) {
  return 0.5f * x * (1.0f + erff(x * 0.70710678118654752440f));
}

// One forward DWT level. xin length n -> a,d length (n+5)/2+1.
// Extension e[i]: i<6 -> x[5-i]; i<n+6 -> x[i-6]; else x[2n+5-i].
// a[j] = sum_k e[2j+k]*LO[7-k];  d[j] = sum_k e[2j+k]*(LO[k]*(-1)^k)
__device__ void dwt_level(const float* xin, int n, float* a, float* d,
                          int tid, int nthr) {
  int outn = (n + 5) / 2 + 1;
  for (int j = tid; j < outn; j += nthr) {
    float sa = 0.f, sd = 0.f;
#pragma unroll
    for (int k = 0; k < 8; ++k) {
      int i = 2 * j + k;
      int idx = (i < 6) ? (5 - i) : ((i < n + 6) ? (i - 6) : (2 * n + 5 - i));
      float v = xin[idx];
      sa += v * W_LO[7 - k];
      sd += v * ((k & 1) ? -W_LO[k] : W_LO[k]);
    }
    a[j] = sa;
    d[j] = sd;
  }
}

// Inverse DWT step: a,d length n (either may be null == zeros) -> out length 2n-6.
// r[t] = sum_{k, j=t-1+k even, 0<=j<=2n-2} a[j/2]*LO[k] + d[j/2]*(LO[7-k]*(-1)^(k+1))
__device__ void idwt_level(const float* a, const float* d, float* out, int n,
                           int tid, int nthr) {
  int outn = 2 * n - 6;
  for (int t = tid; t < outn; t += nthr) {
    float s = 0.f;
#pragma unroll
    for (int k = 0; k < 8; ++k) {
      int j = t - 1 + k;
      if (j >= 0 && j <= 2 * n - 2 && ((j & 1) == 0)) {
        int m = j >> 1;
        if (a) s += a[m] * W_LO[k];
        if (d) s += d[m] * ((k & 1) ? W_LO[7 - k] : -W_LO[7 - k]);
      }
    }
    out[t] = s;
  }
}

// K1: per (row, band): forward DWT 3 levels, then selective reconstruction.
__global__ __launch_bounds__(128) void dwt_bands_kernel(
    const float* __restrict__ x_enc, float* __restrict__ bands) {
  int n = blockIdx.x;     // batch row 0..7 (channel 0 of x_enc)
  int band = blockIdx.y;  // 0..3
  __shared__ float sx[LL];
  __shared__ float a1[259], d1[259], a2[133], d2[133], a3[70], d3[70];
  __shared__ float rA[LL], rB[LL];
  int tid = threadIdx.x;
  for (int l = tid; l < LL; l += 128)
    sx[l] = x_enc[(size_t)n * LL * 32 + (size_t)l * 32];  // channel 0
  __syncthreads();
  dwt_level(sx, 512, a1, d1, tid, 128);
  __syncthreads();
  dwt_level(a1, 259, a2, d2, tid, 128);
  __syncthreads();
  dwt_level(a2, 133, a3, d3, tid, 128);
  __syncthreads();
  // Reconstruction: lengths 70 ->134(trim133) ->260(trim259) ->512
  idwt_level(band == 0 ? a3 : nullptr, band == 1 ? d3 : nullptr, rA, 70, tid, 128);
  __syncthreads();
  idwt_level(rA, band == 2 ? d2 : nullptr, rB, 133, tid, 128);
  __syncthreads();
  idwt_level(rB, band == 3 ? d1 : nullptr, rA, 259, tid, 128);
  __syncthreads();
  float* dst = bands + ((size_t)band * NB + n) * LL;
  for (int l = tid; l < LL; l += 128) dst[l] = rA[l];
}

// K2: cheby. One block = one (band,row,32-pos tile). emb recomputed on the fly.
// bo = sum_k T_k(tanh(emb)) @ C[:,:,k]
__global__ __launch_bounds__(256) void cheby_kernel(
    const float* __restrict__ bands, const float* __restrict__ emb_w, BandW bw,
    float* __restrict__ bo) {
  int blk = blockIdx.x;         // 0..511
  int band = blk >> 7;
  int l0 = (blk & 127) * 32;    // position offset within this band's (n,l) space
  int K = band + 2;
  const float* Cw = bw.cheb[band];
  const float* brow = bands + ((size_t)blk >> 4) * LL;  // (band*8+n) row
  float* dst = bo + (size_t)blk * 32 * DD;

  __shared__ float bl[34];
  __shared__ float xv[32 * 129];
  __shared__ float tp[32 * 129];
  __shared__ float tc[32 * 129];
  int t = threadIdx.x;
  int lbase = l0 & 511;  // position within row
  if (t < 34) bl[t] = brow[(lbase - 1 + t + LL) & 511];  // circular for emb
  __syncthreads();
  for (int idx = t; idx < 32 * DD; idx += 256) {
    int l = idx >> 7, dch = idx & 127;
    float e = emb_w[dch * 3] * bl[l] + emb_w[dch * 3 + 1] * bl[l + 1] +
              emb_w[dch * 3 + 2] * bl[l + 2];
    xv[l * 129 + dch] = tanhf(e);
  }
  __syncthreads();

  int co0 = (t >> 3) << 2;  // 4 output dims per thread
  int p0 = (t & 7) << 2;    // 4 positions per thread
  float acc[4][4];
#pragma unroll
  for (int i = 0; i < 4; ++i)
#pragma unroll
    for (int j = 0; j < 4; ++j) acc[i][j] = 0.f;

  for (int k = 0; k < K; ++k) {
    if (k >= 2) {
      __syncthreads();
      for (int idx = t; idx < 32 * DD; idx += 256) {
        int l = idx >> 7, dch = idx & 127;
        int o = l * 129 + dch;
        if (k == 2) {
          float x = xv[o];
          tp[o] = x;
          tc[o] = 2.f * x * x - 1.f;
        } else {
          float nv = 2.f * xv[o] * tc[o] - tp[o];
          tp[o] = tc[o];
          tc[o] = nv;
        }
      }
      __syncthreads();
    }
    const float* Ck = Cw + k;
    if (k == 0) {  // T0 = 1
      for (int din = 0; din < DD; ++din) {
        const float* cb = Ck + (size_t)din * DD * K + (size_t)co0 * K;
#pragma unroll
        for (int i = 0; i < 4; ++i) {
          float w = cb[i * K];
#pragma unroll
          for (int j = 0; j < 4; ++j) acc[i][j] += w;
        }
      }
    } else {
      const float* Tarr = (k == 1) ? xv : tc;
      for (int din = 0; din < DD; ++din) {
        const float* cb = Ck + (size_t)din * DD * K + (size_t)co0 * K;
        float tv[4];
#pragma unroll
        for (int j = 0; j < 4; ++j) tv[j] = Tarr[(p0 + j) * 129 + din];
#pragma unroll
        for (int i = 0; i < 4; ++i) {
          float w = cb[i * K];
#pragma unroll
          for (int j = 0; j < 4; ++j) acc[i][j] += w * tv[j];
        }
      }
    }
  }
#pragma unroll
  for (int j = 0; j < 4; ++j)
#pragma unroll
    for (int i = 0; i < 4; ++i)
      dst[(size_t)(p0 + j) * DD + co0 + i] = acc[i][j];
}

// K3: TCN conv1 + GELU. emb recomputed on the fly (zero-padded outside [0,512)).
__global__ __launch_bounds__(256) void conv1_kernel(
    const float* __restrict__ bands, const float* __restrict__ emb_w, BandW bw,
    float* __restrict__ y1) {
  int blk = blockIdx.x;
  int band = blk >> 7;
  int l0 = (blk & 15) * 32;
  int dil = 1 << band;  // orders 1,2,3,4 -> dil 1,2,4,8
  const float* W = bw.w1[band];
  const float* Bv = bw.b1[band];
  const float* brow = bands + ((size_t)blk >> 4) * LL;
  float* dst = y1 + ((size_t)blk >> 4) * LL * DD + (size_t)l0 * DD;

  __shared__ float bl2[52];
  __shared__ float tile[48 * 129];
  int rows = 32 + 2 * dil;
  int t = threadIdx.x;
  if (t < rows + 2) bl2[t] = brow[(l0 - dil - 1 + t + LL) & 511];
  __syncthreads();
  for (int idx = t; idx < rows * DD; idx += 256) {
    int rp = idx >> 7, ci = idx & 127;
    int l = l0 - dil + rp;
    float v = 0.f;
    if (l >= 0 && l < LL)
      v = emb_w[ci * 3] * bl2[rp] + emb_w[ci * 3 + 1] * bl2[rp + 1] +
          emb_w[ci * 3 + 2] * bl2[rp + 2];
    tile[rp * 129 + ci] = v;
  }
  __syncthreads();

  int co0 = (t >> 3) << 2;
  int p0 = (t & 7) << 2;
  float acc[4][4];
#pragma unroll
  for (int i = 0; i < 4; ++i) {
    float b = Bv[co0 + i];
#pragma unroll
    for (int j = 0; j < 4; ++j) acc[i][j] = b;
  }
  for (int ci = 0; ci < DD; ++ci) {
    float wv[4][3];
#pragma unroll
    for (int i = 0; i < 4; ++i)
#pragma unroll
      for (int k = 0; k < 3; ++k)
        wv[i][k] = W[(size_t)(co0 + i) * (DD * 3) + ci * 3 + k];
#pragma unroll
    for (int k = 0; k < 3; ++k) {
      int roff = p0 + k * dil;  // tile row of (pos p0+j, tap k)
      float xv4[4];
#pragma unroll
      for (int j = 0; j < 4; ++j) xv4[j] = tile[(roff + j) * 129 + ci];
#pragma unroll
      for (int i = 0; i < 4; ++i)
#pragma unroll
        for (int j = 0; j < 4; ++j) acc[i][j] += wv[i][k] * xv4[j];
    }
  }
#pragma unroll
  for (int j = 0; j < 4; ++j)
#pragma unroll
    for (int i = 0; i < 4; ++i)
      dst[(size_t)(p0 + j) * DD + co0 + i] = gelu_exact(acc[i][j]);
}

// K4: TCN conv2 + GELU + residual emb, accumulated into bo.
__global__ __launch_bounds__(256) void conv2_kernel(
    const float* __restrict__ y1, const float* __restrict__ bands,
    const float* __restrict__ emb_w, BandW bw, float* __restrict__ bo) {
  int blk = blockIdx.x;
  int band = blk >> 7;
  int l0 = (blk & 15) * 32;
  int dil = 1 << band;
  const float* W = bw.w2[band];
  const float* Bv = bw.b2[band];
  const float* brow = bands + ((size_t)blk >> 4) * LL;
  const float* src = y1 + ((size_t)blk >> 4) * LL * DD;
  float* dst = bo + ((size_t)blk >> 4) * LL * DD + (size_t)l0 * DD;

  __shared__ float bl[34];
  __shared__ float tile[48 * 129];
  int rows = 32 + 2 * dil;
  int t = threadIdx.x;
  if (t < 34) bl[t] = brow[(l0 - 1 + t + LL) & 511];
  __syncthreads();
  for (int idx = t; idx < rows * DD; idx += 256) {
    int rp = idx >> 7, ci = idx & 127;
    int l = l0 - dil + rp;
    tile[rp * 129 + ci] = (l >= 0 && l < LL) ? src[(size_t)l * DD + ci] : 0.f;
  }
  __syncthreads();

  int co0 = (t >> 3) << 2;
  int p0 = (t & 7) << 2;
  float acc[4][4];
#pragma unroll
  for (int i = 0; i < 4; ++i) {
    float b = Bv[co0 + i];
#pragma unroll
    for (int j = 0; j < 4; ++j) acc[i][j] = b;
  }
  for (int ci = 0; ci < DD; ++ci) {
    float wv[4][3];
#pragma unroll
    for (int i = 0; i < 4; ++i)
#pragma unroll
      for (int k = 0; k < 3; ++k)
        wv[i][k] = W[(size_t)(co0 + i) * (DD * 3) + ci * 3 + k];
#pragma unroll
    for (int k = 0; k < 3; ++k) {
      int roff = p0 + k * dil;
      float xv4[4];
#pragma unroll
      for (int j = 0; j < 4; ++j) xv4[j] = tile[(roff + j) * 129 + ci];
#pragma unroll
      for (int i = 0; i < 4; ++i)
#pragma unroll
        for (int j = 0; j < 4; ++j) acc[i][j] += wv[i][k] * xv4[j];
    }
  }
#pragma unroll
  for (int j = 0; j < 4; ++j) {
#pragma unroll
    for (int i = 0; i < 4; ++i) {
      // residual emb at (l0+p0+j, co0+i): bl[p]=band[l0+p-1]
      float e = emb_w[(co0 + i) * 3] * bl[p0 + j] +
                emb_w[(co0 + i) * 3 + 1] * bl[p0 + j + 1] +
                emb_w[(co0 + i) * 3 + 2] * bl[p0 + j + 2];
      size_t o = (size_t)(p0 + j) * DD + co0 + i;
      dst[o] = dst[o] + gelu_exact(acc[i][j]) + e;
    }
  }
}

// K5: head. fused = sum_bands bo; h[p,d] = sum_l fused[l,d]*pred_w[p,l] + pred_b[p];
// out[p,q] = sum_d h[p,d]*proj_w[q,d] + proj_b[q]
__global__ __launch_bounds__(256) void head_kernel(
    const float* __restrict__ bo, const float* __restrict__ pred_w,
    const float* __restrict__ pred_b, const float* __restrict__ proj_w,
    const float* __restrict__ proj_b, float* __restrict__ out) {
  int n = blockIdx.x;   // 0..7
  int pt = blockIdx.y;  // 0..5 (16 p each)
  __shared__ float fch[64 * DD];
  int t = threadIdx.x;
  int d = t & 127;
  int ph = t >> 7;  // 0..1
  float acc[8];
#pragma unroll
  for (int j = 0; j < 8; ++j) acc[j] = 0.f;
  const size_t bstride = (size_t)NB * LL * DD;
  for (int l0 = 0; l0 < LL; l0 += 64) {
    __syncthreads();
    for (int idx = t; idx < 64 * DD; idx += 256) {
      int l = idx >> 7, dd2 = idx & 127;
      size_t base = ((size_t)n * LL + (l0 + l)) * DD + dd2;
      fch[idx] = bo[base] + bo[base + bstride] + bo[base + 2 * bstride] +
                 bo[base + 3 * bstride];
    }
    __syncthreads();
    for (int l = 0; l < 64; ++l) {
      float f = fch[l * DD + d];
#pragma unroll
      for (int j = 0; j < 8; ++j) {
        int p = pt * 16 + ph + 2 * j;
        acc[j] += f * pred_w[(size_t)p * LL + l0 + l];
      }
    }
  }
  __syncthreads();
#pragma unroll
  for (int j = 0; j < 8; ++j) {
    int pl = ph + 2 * j;
    fch[pl * DD + d] = acc[j] + pred_b[pt * 16 + pl];
  }
  __syncthreads();
  if (t < 48) {
    int pl = t / 3, q = t % 3;
    float s = proj_b[q];
    for (int dd2 = 0; dd2 < DD; ++dd2)
      s += fch[pl * DD + dd2] * proj_w[q * DD + dd2];
    out[(size_t)n * (PP * QQ) + (size_t)(pt * 16 + pl) * QQ + q] = s;
  }
}

extern "C" void kernel_launch(void* const* d_in, const int* in_sizes, int n_in,
                              void* d_out, int out_size, void* d_ws, size_t ws_size,
                              hipStream_t stream) {
  const float* x_enc = (const float*)d_in[0];
  const float* emb_w = (const float*)d_in[1];
  BandW bw;
  for (int i = 0; i < 4; ++i) {
    bw.cheb[i] = (const float*)d_in[2 + 5 * i];
    bw.w1[i] = (const float*)d_in[3 + 5 * i];
    bw.b1[i] = (const float*)d_in[4 + 5 * i];
    bw.w2[i] = (const float*)d_in[5 + 5 * i];
    bw.b2[i] = (const float*)d_in[6 + 5 * i];
  }
  const float* proj_w = (const float*)d_in[22];
  const float* proj_b = (const float*)d_in[23];
  const float* pred_w = (const float*)d_in[24];
  const float* pred_b = (const float*)d_in[25];
  float* ws = (float*)d_ws;
  float* bands = ws;                         // 4*8*512        = 16384 floats
  float* y1 = ws + 16384;                    // 4*8*512*128    = 2097152 floats
  float* bo = y1 + 2097152;                  // 4*8*512*128    = 2097152 floats
  float* out = (float*)d_out;

  dwt_bands_kernel<<<dim3(NB, 4), 128, 0, stream>>>(x_enc, bands);
  cheby_kernel<<<512, 256, 0, stream>>>(bands, emb_w, bw, bo);
  conv1_kernel<<<512, 256, 0, stream>>>(bands, emb_w, bw, y1);
  conv2_kernel<<<512, 256, 0, stream>>>(y1, bands, emb_w, bw, bo);
  head_kernel<<<dim3(NB, 6), 256, 0, stream>>>(bo, pred_w, pred_b, proj_w,
                                               proj_b, out);
}

// Round 2
// 186.027 us; speedup vs baseline: 1.1529x; 1.1529x over previous
//
#include <hip/hip_runtime.h>
#include <math.h>

#define NB 8      // only channel 0 of C=32 survives the final slice
#define LL 512
#define DD 128
#define PP 96
#define QQ 3

// workspace layout (floats)
#define WS_BANDS 0
#define WS_Y1    16384
#define WS_BO    (16384 + 2097152)
#define WS_CT    (16384 + 2 * 2097152)
#define WS_B0    (WS_CT + 163840)
#define WS_WT    (WS_B0 + 512)

// db4 low-pass (pywt)
constexpr float W_LO[8] = {
  -0.010597401784997278f, 0.032883011666982945f, 0.030841381835986965f,
  -0.18703481171888114f, -0.02798376941698385f, 0.6308807679295904f,
  0.7148465705525415f, 0.23037781330885523f
};

__device__ __forceinline__ float gelu_exact(float x) {
  return 0.5f * x * (1.0f + erff(x * 0.70710678118654752440f));
}

// ---------------- DWT helpers (validated round 0) ----------------
__device__ void dwt_level(const float* xin, int n, float* a, float* d,
                          int tid, int nthr) {
  int outn = (n + 5) / 2 + 1;
  for (int j = tid; j < outn; j += nthr) {
    float sa = 0.f, sd = 0.f;
#pragma unroll
    for (int k = 0; k < 8; ++k) {
      int i = 2 * j + k;
      int idx = (i < 6) ? (5 - i) : ((i < n + 6) ? (i - 6) : (2 * n + 5 - i));
      float v = xin[idx];
      sa += v * W_LO[7 - k];
      sd += v * ((k & 1) ? -W_LO[k] : W_LO[k]);
    }
    a[j] = sa;
    d[j] = sd;
  }
}

__device__ void idwt_level(const float* a, const float* d, float* out, int n,
                           int tid, int nthr) {
  int outn = 2 * n - 6;
  for (int t = tid; t < outn; t += nthr) {
    float s = 0.f;
#pragma unroll
    for (int k = 0; k < 8; ++k) {
      int j = t - 1 + k;
      if (j >= 0 && j <= 2 * n - 2 && ((j & 1) == 0)) {
        int m = j >> 1;
        if (a) s += a[m] * W_LO[k];
        if (d) s += d[m] * ((k & 1) ? W_LO[7 - k] : -W_LO[7 - k]);
      }
    }
    out[t] = s;
  }
}

// ---------------- K0: DWT + weight transpose roles ----------------
struct PrepArgs {
  const float* x_enc;
  const float* cheb[4];
  const float* w1[4];
  const float* w2[4];
  float* bands;
  float* ct;   // [slice 0..9][din][dout], slices = T_1..T_{K-1} per band, band offsets {0,1,3,6}
  float* b0;   // [band][dout] = sum_din C[din][dout][0]
  float* wt;   // [(band*2+which)*3 + tap][din][dout]
};

__global__ __launch_bounds__(256) void prep_kernel(PrepArgs a) {
  __shared__ float sx[LL];
  __shared__ float a1[259], d1[259], a2[133], d2[133], a3[70], d3[70];
  __shared__ float rA[LL], rB[LL];
  int bid = blockIdx.x, t = threadIdx.x;
  if (bid < 32) {
    int n = bid & 7, band = bid >> 3;
    for (int l = t; l < LL; l += 256)
      sx[l] = a.x_enc[(size_t)n * LL * 32 + (size_t)l * 32];  // channel 0
    __syncthreads();
    dwt_level(sx, 512, a1, d1, t, 256); __syncthreads();
    dwt_level(a1, 259, a2, d2, t, 256); __syncthreads();
    dwt_level(a2, 133, a3, d3, t, 256); __syncthreads();
    idwt_level(band == 0 ? a3 : nullptr, band == 1 ? d3 : nullptr, rA, 70, t, 256);
    __syncthreads();
    idwt_level(rA, band == 2 ? d2 : nullptr, rB, 133, t, 256);
    __syncthreads();
    idwt_level(rB, band == 3 ? d1 : nullptr, rA, 259, t, 256);
    __syncthreads();
    float* dstb = a.bands + ((size_t)band * NB + n) * LL;
    for (int l = t; l < LL; l += 256) dstb[l] = rA[l];
  } else {
    const int CT_N = 163840, WT_N = 393216, B0_N = 512;
    int total = CT_N + WT_N + B0_N;
    for (int e = (bid - 32) * 256 + t; e < total; e += 256 * 256) {
      if (e < CT_N) {
        int s = e >> 14, r = e & 16383;
        int b = (s >= 6) ? 3 : ((s >= 3) ? 2 : ((s >= 1) ? 1 : 0));
        int off = (b == 3) ? 6 : ((b == 2) ? 3 : ((b == 1) ? 1 : 0));
        int kk = s - off;
        int K = b + 2;
        int din = r >> 7, dout = r & 127;
        a.ct[e] = a.cheb[b][((size_t)din * DD + dout) * K + kk + 1];
      } else if (e < CT_N + WT_N) {
        int e2 = e - CT_N;
        int m = e2 / 49152;
        int r = e2 - m * 49152;
        int b = m >> 1, which = m & 1;
        int tap = r >> 14, t2 = r & 16383;
        int din = t2 >> 7, dout = t2 & 127;
        const float* w = which ? a.w2[b] : a.w1[b];
        a.wt[e2] = w[(size_t)dout * 384 + din * 3 + tap];
      } else {
        int e3 = e - CT_N - WT_N;
        int b = e3 >> 7, dout = e3 & 127;
        int K = b + 2;
        const float* cw = a.cheb[b];
        float s2 = 0.f;
        for (int din = 0; din < DD; ++din) s2 += cw[((size_t)din * DD + dout) * K];
        a.b0[e3] = s2;
      }
    }
  }
}

// ---------------- matmul kernels ----------------
struct MainArgs {
  const float* emb_w;
  const float* bands;
  const float* ct;
  const float* b0;
  const float* wt;
  const float* b1[4];
  const float* b2[4];
  float* y1;
  float* bo;
};

// cheby role: 32-pos tile, NK = K-1 planes (T_1..T_{K-1}); T_0 folded into bias b0.
template <int NK>
__device__ __forceinline__ void cheby_core(
    const float* __restrict__ brow, const float* __restrict__ emb_w,
    const float* __restrict__ ctb, const float* __restrict__ b0b,
    float* __restrict__ dst, int l0, float* planes, float* blx) {
  int t = threadIdx.x;
  if (t < 34) blx[t] = brow[(l0 - 1 + t + LL) & 511];
  int co0 = (t & 31) << 2, p0 = (t >> 5) << 2;
  float acc[4][4];
#pragma unroll
  for (int i = 0; i < 4; ++i) {
    float b = b0b[co0 + i];
#pragma unroll
    for (int j = 0; j < 4; ++j) acc[i][j] = b;
  }
  for (int c0 = 0; c0 < DD; c0 += 32) {
    __syncthreads();
    // build T planes for din chunk [c0, c0+32), layout planes[(k*32+di)*36 + l]
    for (int idx = t; idx < 1024; idx += 256) {
      int l = idx & 31, di = idx >> 5;
      int dch = c0 + di;
      float e = emb_w[dch * 3] * blx[l] + emb_w[dch * 3 + 1] * blx[l + 1] +
                emb_w[dch * 3 + 2] * blx[l + 2];
      float x = tanhf(e);
      planes[di * 36 + l] = x;
      if (NK >= 2) {
        float t2 = 2.f * x * x - 1.f;
        planes[(32 + di) * 36 + l] = t2;
        if (NK >= 3) {
          float t3 = 2.f * x * t2 - x;
          planes[(64 + di) * 36 + l] = t3;
          if (NK >= 4) planes[(96 + di) * 36 + l] = 2.f * x * t3 - t2;
        }
      }
    }
    __syncthreads();
    const float* cb = ctb + (size_t)c0 * DD + co0;
    for (int di = 0; di < 32; ++di) {
      const float* cp = cb + (size_t)di * DD;
#pragma unroll
      for (int k = 0; k < NK; ++k) {
        float4 w = *(const float4*)(cp + (size_t)k * 16384);
        float4 av = *(const float4*)&planes[(k * 32 + di) * 36 + p0];
        float wv[4] = {w.x, w.y, w.z, w.w};
        float aa[4] = {av.x, av.y, av.z, av.w};
#pragma unroll
        for (int i = 0; i < 4; ++i)
#pragma unroll
          for (int j = 0; j < 4; ++j) acc[i][j] += wv[i] * aa[j];
      }
    }
  }
#pragma unroll
  for (int j = 0; j < 4; ++j) {
    float4 r = make_float4(acc[0][j], acc[1][j], acc[2][j], acc[3][j]);
    *(float4*)&dst[(size_t)(p0 + j) * DD + co0] = r;
  }
}

// conv role: 32-pos tile; SECOND = conv2 (+gelu +emb residual, accumulate into bo)
template <int DIL, bool SECOND>
__device__ __forceinline__ void conv_role(
    const float* __restrict__ brow, const float* __restrict__ emb_w,
    const float* __restrict__ wtb, const float* __restrict__ bias,
    const float* __restrict__ srcrow, float* __restrict__ dstrow, int l0,
    float* tile, float* blx) {
  const int rows = 32 + 2 * DIL;
  int t = threadIdx.x;
  if (SECOND) {
    if (t < 34) blx[t] = brow[(l0 - 1 + t + LL) & 511];
  } else {
    if (t < rows + 2) blx[t] = brow[(l0 - DIL - 1 + t + LL) & 511];
  }
  __syncthreads();
  for (int idx = t; idx < rows * DD; idx += 256) {
    int ci = idx & 127, rp = idx >> 7;
    int l = l0 - DIL + rp;
    float v = 0.f;
    if (l >= 0 && l < LL) {
      if (SECOND)
        v = srcrow[(size_t)l * DD + ci];
      else
        v = emb_w[ci * 3] * blx[rp] + emb_w[ci * 3 + 1] * blx[rp + 1] +
            emb_w[ci * 3 + 2] * blx[rp + 2];
    }
    tile[ci * 49 + rp] = v;  // [din][rows], stride 49 -> conflict-free
  }
  __syncthreads();
  int co0 = (t & 31) << 2, p0 = (t >> 5) << 2;
  float acc[4][4];
#pragma unroll
  for (int i = 0; i < 4; ++i) {
    float b = bias[co0 + i];
#pragma unroll
    for (int j = 0; j < 4; ++j) acc[i][j] = b;
  }
  for (int din = 0; din < DD; ++din) {
    const float* xr = &tile[din * 49 + p0];
    const float* wp = wtb + (size_t)din * DD + co0;
#pragma unroll
    for (int tap = 0; tap < 3; ++tap) {
      float4 w = *(const float4*)(wp + (size_t)tap * 16384);
      const float* xo = xr + tap * DIL;
      float a0 = xo[0], a1v = xo[1], a2v = xo[2], a3v = xo[3];
      float wv[4] = {w.x, w.y, w.z, w.w};
#pragma unroll
      for (int i = 0; i < 4; ++i) {
        acc[i][0] += wv[i] * a0;
        acc[i][1] += wv[i] * a1v;
        acc[i][2] += wv[i] * a2v;
        acc[i][3] += wv[i] * a3v;
      }
    }
  }
#pragma unroll
  for (int j = 0; j < 4; ++j) {
    float g0 = gelu_exact(acc[0][j]), g1 = gelu_exact(acc[1][j]);
    float g2 = gelu_exact(acc[2][j]), g3 = gelu_exact(acc[3][j]);
    float4 r;
    if (SECOND) {
      float4 old = *(const float4*)&dstrow[(size_t)(l0 + p0 + j) * DD + co0];
      float bj0 = blx[p0 + j], bj1 = blx[p0 + j + 1], bj2 = blx[p0 + j + 2];
      float e0 = emb_w[(co0 + 0) * 3] * bj0 + emb_w[(co0 + 0) * 3 + 1] * bj1 + emb_w[(co0 + 0) * 3 + 2] * bj2;
      float e1 = emb_w[(co0 + 1) * 3] * bj0 + emb_w[(co0 + 1) * 3 + 1] * bj1 + emb_w[(co0 + 1) * 3 + 2] * bj2;
      float e2 = emb_w[(co0 + 2) * 3] * bj0 + emb_w[(co0 + 2) * 3 + 1] * bj1 + emb_w[(co0 + 2) * 3 + 2] * bj2;
      float e3 = emb_w[(co0 + 3) * 3] * bj0 + emb_w[(co0 + 3) * 3 + 1] * bj1 + emb_w[(co0 + 3) * 3 + 2] * bj2;
      r = make_float4(old.x + g0 + e0, old.y + g1 + e1, old.z + g2 + e2, old.w + g3 + e3);
    } else {
      r = make_float4(g0, g1, g2, g3);
    }
    *(float4*)&dstrow[(size_t)(l0 + p0 + j) * DD + co0] = r;
  }
}

// K2: blocks [0,512) = cheby, [512,1024) = conv1
__global__ __launch_bounds__(256) void main2_kernel(MainArgs ar) {
  __shared__ float smem[6272];
  __shared__ float blx[64];
  int bid = blockIdx.x;
  if (bid < 512) {
    int band = bid >> 7, n = (bid >> 4) & 7, l0 = (bid & 15) * 32;
    const float* brow = ar.bands + ((size_t)band * NB + n) * LL;
    const int ctoff[4] = {0, 1, 3, 6};
    const float* ctb = ar.ct + (size_t)ctoff[band] * 16384;
    const float* b0b = ar.b0 + band * DD;
    float* dst = ar.bo + (((size_t)band * NB + n) * LL + l0) * DD;
    switch (band) {
      case 0: cheby_core<1>(brow, ar.emb_w, ctb, b0b, dst, l0, smem, blx); break;
      case 1: cheby_core<2>(brow, ar.emb_w, ctb, b0b, dst, l0, smem, blx); break;
      case 2: cheby_core<3>(brow, ar.emb_w, ctb, b0b, dst, l0, smem, blx); break;
      default: cheby_core<4>(brow, ar.emb_w, ctb, b0b, dst, l0, smem, blx); break;
    }
  } else {
    int b2 = bid - 512;
    int band = b2 >> 7, n = (b2 >> 4) & 7, l0 = (b2 & 15) * 32;
    const float* brow = ar.bands + ((size_t)band * NB + n) * LL;
    const float* wtb = ar.wt + (size_t)(band * 2) * 3 * 16384;
    float* dstrow = ar.y1 + ((size_t)band * NB + n) * LL * DD;
    switch (band) {
      case 0: conv_role<1, false>(brow, ar.emb_w, wtb, ar.b1[0], nullptr, dstrow, l0, smem, blx); break;
      case 1: conv_role<2, false>(brow, ar.emb_w, wtb, ar.b1[1], nullptr, dstrow, l0, smem, blx); break;
      case 2: conv_role<4, false>(brow, ar.emb_w, wtb, ar.b1[2], nullptr, dstrow, l0, smem, blx); break;
      default: conv_role<8, false>(brow, ar.emb_w, wtb, ar.b1[3], nullptr, dstrow, l0, smem, blx); break;
    }
  }
}

// K3: conv2 (+gelu +emb residual, accumulates into bo on top of cheby output)
__global__ __launch_bounds__(256) void conv2k_kernel(MainArgs ar) {
  __shared__ float smem[6272];
  __shared__ float blx[64];
  int bid = blockIdx.x;
  int band = bid >> 7, n = (bid >> 4) & 7, l0 = (bid & 15) * 32;
  const float* brow = ar.bands + ((size_t)band * NB + n) * LL;
  const float* wtb = ar.wt + (size_t)(band * 2 + 1) * 3 * 16384;
  const float* srcrow = ar.y1 + ((size_t)band * NB + n) * LL * DD;
  float* dstrow = ar.bo + ((size_t)band * NB + n) * LL * DD;
  switch (band) {
    case 0: conv_role<1, true>(brow, ar.emb_w, wtb, ar.b2[0], srcrow, dstrow, l0, smem, blx); break;
    case 1: conv_role<2, true>(brow, ar.emb_w, wtb, ar.b2[1], srcrow, dstrow, l0, smem, blx); break;
    case 2: conv_role<4, true>(brow, ar.emb_w, wtb, ar.b2[2], srcrow, dstrow, l0, smem, blx); break;
    default: conv_role<8, true>(brow, ar.emb_w, wtb, ar.b2[3], srcrow, dstrow, l0, smem, blx); break;
  }
}

// K4: head (validated round 0)
__global__ __launch_bounds__(256) void head_kernel(
    const float* __restrict__ bo, const float* __restrict__ pred_w,
    const float* __restrict__ pred_b, const float* __restrict__ proj_w,
    const float* __restrict__ proj_b, float* __restrict__ out) {
  int n = blockIdx.x;
  int pt = blockIdx.y;
  __shared__ float fch[64 * DD];
  int t = threadIdx.x;
  int d = t & 127;
  int ph = t >> 7;
  float acc[8];
#pragma unroll
  for (int j = 0; j < 8; ++j) acc[j] = 0.f;
  const size_t bstride = (size_t)NB * LL * DD;
  for (int l0 = 0; l0 < LL; l0 += 64) {
    __syncthreads();
    for (int idx = t; idx < 64 * DD; idx += 256) {
      int l = idx >> 7, dd2 = idx & 127;
      size_t base = ((size_t)n * LL + (l0 + l)) * DD + dd2;
      fch[idx] = bo[base] + bo[base + bstride] + bo[base + 2 * bstride] +
                 bo[base + 3 * bstride];
    }
    __syncthreads();
    for (int l = 0; l < 64; ++l) {
      float f = fch[l * DD + d];
#pragma unroll
      for (int j = 0; j < 8; ++j) {
        int p = pt * 16 + ph + 2 * j;
        acc[j] += f * pred_w[(size_t)p * LL + l0 + l];
      }
    }
  }
  __syncthreads();
#pragma unroll
  for (int j = 0; j < 8; ++j) {
    int pl = ph + 2 * j;
    fch[pl * DD + d] = acc[j] + pred_b[pt * 16 + pl];
  }
  __syncthreads();
  if (t < 48) {
    int pl = t / 3, q = t % 3;
    float s = proj_b[q];
    for (int dd2 = 0; dd2 < DD; ++dd2)
      s += fch[pl * DD + dd2] * proj_w[q * DD + dd2];
    out[(size_t)n * (PP * QQ) + (size_t)(pt * 16 + pl) * QQ + q] = s;
  }
}

extern "C" void kernel_launch(void* const* d_in, const int* in_sizes, int n_in,
                              void* d_out, int out_size, void* d_ws, size_t ws_size,
                              hipStream_t stream) {
  const float* x_enc = (const float*)d_in[0];
  const float* emb_w = (const float*)d_in[1];
  const float* proj_w = (const float*)d_in[22];
  const float* proj_b = (const float*)d_in[23];
  const float* pred_w = (const float*)d_in[24];
  const float* pred_b = (const float*)d_in[25];
  float* ws = (float*)d_ws;
  float* bands = ws + WS_BANDS;
  float* y1 = ws + WS_Y1;
  float* bo = ws + WS_BO;
  float* ct = ws + WS_CT;
  float* b0 = ws + WS_B0;
  float* wt = ws + WS_WT;
  float* out = (float*)d_out;

  PrepArgs pa;
  pa.x_enc = x_enc;
  for (int i = 0; i < 4; ++i) {
    pa.cheb[i] = (const float*)d_in[2 + 5 * i];
    pa.w1[i] = (const float*)d_in[3 + 5 * i];
    pa.w2[i] = (const float*)d_in[5 + 5 * i];
  }
  pa.bands = bands; pa.ct = ct; pa.b0 = b0; pa.wt = wt;

  MainArgs ma;
  ma.emb_w = emb_w; ma.bands = bands; ma.ct = ct; ma.b0 = b0; ma.wt = wt;
  for (int i = 0; i < 4; ++i) {
    ma.b1[i] = (const float*)d_in[4 + 5 * i];
    ma.b2[i] = (const float*)d_in[6 + 5 * i];
  }
  ma.y1 = y1; ma.bo = bo;

  prep_kernel<<<288, 256, 0, stream>>>(pa);
  main2_kernel<<<1024, 256, 0, stream>>>(ma);
  conv2k_kernel<<<512, 256, 0, stream>>>(ma);
  head_kernel<<<dim3(NB, 6), 256, 0, stream>>>(bo, pred_w, pred_b, proj_w,
                                               proj_b, out);
}

// Round 3
// 68.331 us; speedup vs baseline: 3.1386x; 2.7224x over previous
//
#include <hip/hip_runtime.h>
#include <math.h>

#define NB 8      // only channel 0 of C=32 survives the final slice
#define LL 512
#define DD 128
#define PP 96
#define QQ 3

// workspace layout (float offsets)
#define WS_BANDS 0
#define WS_BO    16384
#define WS_Y1    (16384 + 2097152)              // bf16 (shorts), 2097152 shorts
#define WS_H     (WS_Y1 + 1048576)              // 8*96*128 f32
#define WS_CFR   (WS_H + 98304)                 // 163840 shorts
#define WS_WFR   (WS_CFR + 81920)               // 393216 shorts
#define WS_PFR   (WS_WFR + 196608)              // 49152 shorts
#define WS_B0    (WS_PFR + 24576)               // 512 f32

typedef __attribute__((ext_vector_type(8))) short short8v;
typedef __attribute__((ext_vector_type(4))) short short4v;
typedef __attribute__((ext_vector_type(4))) float f32x4;

#define MFMA16(a, b, c) __builtin_amdgcn_mfma_f32_16x16x32_bf16(a, b, c, 0, 0, 0)

__device__ __forceinline__ short f2bf(float f) {
  unsigned u = __builtin_bit_cast(unsigned, f);
  unsigned r = (u + 0x7fffu + ((u >> 16) & 1u)) >> 16;
  return (short)r;
}

__device__ __forceinline__ float gelu_exact(float x) {
  return 0.5f * x * (1.0f + erff(x * 0.70710678118654752440f));
}

constexpr float W_LO[8] = {
  -0.010597401784997278f, 0.032883011666982945f, 0.030841381835986965f,
  -0.18703481171888114f, -0.02798376941698385f, 0.6308807679295904f,
  0.7148465705525415f, 0.23037781330885523f
};

// ---------------- DWT helpers (validated round 0/1) ----------------
__device__ void dwt_level(const float* xin, int n, float* a, float* d,
                          int tid, int nthr) {
  int outn = (n + 5) / 2 + 1;
  for (int j = tid; j < outn; j += nthr) {
    float sa = 0.f, sd = 0.f;
#pragma unroll
    for (int k = 0; k < 8; ++k) {
      int i = 2 * j + k;
      int idx = (i < 6) ? (5 - i) : ((i < n + 6) ? (i - 6) : (2 * n + 5 - i));
      float v = xin[idx];
      sa += v * W_LO[7 - k];
      sd += v * ((k & 1) ? -W_LO[k] : W_LO[k]);
    }
    a[j] = sa;
    d[j] = sd;
  }
}

__device__ void idwt_level(const float* a, const float* d, float* out, int n,
                           int tid, int nthr) {
  int outn = 2 * n - 6;
  for (int t = tid; t < outn; t += nthr) {
    float s = 0.f;
#pragma unroll
    for (int k = 0; k < 8; ++k) {
      int j = t - 1 + k;
      if (j >= 0 && j <= 2 * n - 2 && ((j & 1) == 0)) {
        int m = j >> 1;
        if (a) s += a[m] * W_LO[k];
        if (d) s += d[m] * ((k & 1) ? W_LO[7 - k] : -W_LO[7 - k]);
      }
    }
    out[t] = s;
  }
}

// ---------------- K0: DWT (32 blocks) + weight fragment packing ----------------
struct PrepArgs {
  const float* x_enc;
  const float* cheb[4];
  const float* w1[4];
  const float* w2[4];
  const float* pred_w;
  float* bands;
  short* cfr;  // [slice10][ks4][nt8][lane64][e8]
  short* wfr;  // [(band*2+which)*3+tap][ks4][nt8][lane64][e8]
  short* pfr;  // [ks16][mt6][lane64][e8]
  float* b0;   // [band][dout]
};

__global__ __launch_bounds__(256) void prep_kernel(PrepArgs a) {
  __shared__ float sx[LL];
  __shared__ float a1[259], d1[259], a2[133], d2[133], a3[70], d3[70];
  __shared__ float rA[LL], rB[LL];
  int bid = blockIdx.x, t = threadIdx.x;
  if (bid < 32) {
    int n = bid & 7, band = bid >> 3;
    for (int l = t; l < LL; l += 256)
      sx[l] = a.x_enc[(size_t)n * LL * 32 + (size_t)l * 32];  // channel 0
    __syncthreads();
    dwt_level(sx, 512, a1, d1, t, 256); __syncthreads();
    dwt_level(a1, 259, a2, d2, t, 256); __syncthreads();
    dwt_level(a2, 133, a3, d3, t, 256); __syncthreads();
    idwt_level(band == 0 ? a3 : nullptr, band == 1 ? d3 : nullptr, rA, 70, t, 256);
    __syncthreads();
    idwt_level(rA, band == 2 ? d2 : nullptr, rB, 133, t, 256);
    __syncthreads();
    idwt_level(rB, band == 3 ? d1 : nullptr, rA, 259, t, 256);
    __syncthreads();
    float* dstb = a.bands + ((size_t)band * NB + n) * LL;
    for (int l = t; l < LL; l += 256) dstb[l] = rA[l];
  } else {
    const int CFR_N = 163840, WFR_N = 393216, PFR_N = 49152, B0_N = 512;
    const int total = CFR_N + WFR_N + PFR_N + B0_N;
    for (int e = (bid - 32) * 256 + t; e < total; e += 128 * 256) {
      if (e < CFR_N) {
        int s = e >> 14, r = e & 16383;
        int ks = r >> 12, r2 = r & 4095;
        int nt = r2 >> 9, r3 = r2 & 511;
        int lane = r3 >> 3, el = r3 & 7;
        int b = (s >= 6) ? 3 : ((s >= 3) ? 2 : ((s >= 1) ? 1 : 0));
        int off = (b == 3) ? 6 : ((b == 2) ? 3 : ((b == 1) ? 1 : 0));
        int kl = s - off;
        int K = b + 2;
        int din = ks * 32 + (lane >> 4) * 8 + el;
        int dout = nt * 16 + (lane & 15);
        a.cfr[e] = f2bf(a.cheb[b][((size_t)din * DD + dout) * K + kl + 1]);
      } else if (e < CFR_N + WFR_N) {
        int e2 = e - CFR_N;
        int m = e2 >> 14, r = e2 & 16383;  // m = (band*2+which)*3+tap
        int ks = r >> 12, r2 = r & 4095;
        int nt = r2 >> 9, r3 = r2 & 511;
        int lane = r3 >> 3, el = r3 & 7;
        int bw = m / 3, tap = m - bw * 3;
        int band = bw >> 1, which = bw & 1;
        const float* w = which ? a.w2[band] : a.w1[band];
        int din = ks * 32 + (lane >> 4) * 8 + el;
        int dout = nt * 16 + (lane & 15);
        a.wfr[e2] = f2bf(w[((size_t)dout * DD + din) * 3 + tap]);
      } else if (e < CFR_N + WFR_N + PFR_N) {
        int e3 = e - CFR_N - WFR_N;
        int ks = e3 / 3072, r = e3 - ks * 3072;
        int mt = r >> 9, r3 = r & 511;
        int lane = r3 >> 3, el = r3 & 7;
        int p = mt * 16 + (lane & 15);
        int l = ks * 32 + (lane >> 4) * 8 + el;
        a.pfr[e3] = f2bf(a.pred_w[(size_t)p * LL + l]);
      } else {
        int e4 = e - CFR_N - WFR_N - PFR_N;
        int b = e4 >> 7, dout = e4 & 127;
        int K = b + 2;
        const float* cw = a.cheb[b];
        float s2 = 0.f;
        for (int din = 0; din < DD; ++din) s2 += cw[((size_t)din * DD + dout) * K];
        a.b0[e4] = s2;
      }
    }
  }
}

// ---------------- MFMA roles ----------------
struct MainArgs {
  const float* emb_w;
  const float* bands;
  const short* cfr;
  const short* wfr;
  const float* b1[4];
  const float* b2[4];
  const float* b0;
  short* y1;
  float* bo;
};

// cheby: out tile 32 pos x 128 dout; A = T_k planes (bf16 LDS), B = cfr frags.
template <int NK>
__device__ __forceinline__ void cheby_core_mfma(
    const MainArgs& ar, int band, int n, int l0, short* sA, float* blx) {
  int t = threadIdx.x;
  const float* brow = ar.bands + ((size_t)band * NB + n) * LL;
  if (t < 34) blx[t] = brow[(l0 - 1 + t + LL) & 511];
  __syncthreads();
  const float* ew = ar.emb_w;
  for (int idx = t; idx < 32 * DD; idx += 256) {
    int l = idx >> 7, dch = idx & 127;
    float e = ew[dch * 3] * blx[l] + ew[dch * 3 + 1] * blx[l + 1] +
              ew[dch * 3 + 2] * blx[l + 2];
    float x = tanhf(e);
    int o = l * 136 + dch;
    sA[o] = f2bf(x);
    if (NK >= 2) {
      float t2 = 2.f * x * x - 1.f;
      sA[4352 + o] = f2bf(t2);
      if (NK >= 3) {
        float t3 = 2.f * x * t2 - x;
        sA[8704 + o] = f2bf(t3);
        if (NK >= 4) sA[13056 + o] = f2bf(2.f * x * t3 - t2);
      }
    }
  }
  __syncthreads();

  int w = t >> 6, lane = t & 63;
  int r16 = lane & 15, kq = lane >> 4;
  const int sbase = (band == 3) ? 6 : ((band == 2) ? 3 : ((band == 1) ? 1 : 0));
  const short8v* cfrv = (const short8v*)ar.cfr;
  f32x4 acc[2][2];
#pragma unroll
  for (int i = 0; i < 2; ++i)
#pragma unroll
    for (int j = 0; j < 2; ++j) acc[i][j] = (f32x4){0.f, 0.f, 0.f, 0.f};

#pragma unroll
  for (int s = 0; s < NK; ++s) {
#pragma unroll
    for (int ks = 0; ks < 4; ++ks) {
      short8v a0 = *(const short8v*)&sA[s * 4352 + r16 * 136 + ks * 32 + kq * 8];
      short8v a1 = *(const short8v*)&sA[s * 4352 + (16 + r16) * 136 + ks * 32 + kq * 8];
      short8v bf0 = cfrv[(((sbase + s) * 4 + ks) * 8 + w * 2 + 0) * 64 + lane];
      short8v bf1 = cfrv[(((sbase + s) * 4 + ks) * 8 + w * 2 + 1) * 64 + lane];
      acc[0][0] = MFMA16(a0, bf0, acc[0][0]);
      acc[0][1] = MFMA16(a0, bf1, acc[0][1]);
      acc[1][0] = MFMA16(a1, bf0, acc[1][0]);
      acc[1][1] = MFMA16(a1, bf1, acc[1][1]);
    }
  }
  int row0 = kq * 4;
  float* borow = ar.bo + (((size_t)band * NB + n) * LL + l0) * DD;
#pragma unroll
  for (int nt = 0; nt < 2; ++nt) {
    int dout = w * 32 + nt * 16 + r16;
    float b0v = ar.b0[band * DD + dout];
#pragma unroll
    for (int m = 0; m < 2; ++m)
#pragma unroll
      for (int r = 0; r < 4; ++r)
        borow[(size_t)(m * 16 + row0 + r) * DD + dout] = acc[m][nt][r] + b0v;
  }
}

// conv: SECOND=false -> conv1 (A=emb tile, out=gelu -> y1 bf16)
//       SECOND=true  -> conv2 (A=y1 tile, out=bo += gelu + emb residual)
template <int DIL, bool SECOND>
__device__ __forceinline__ void conv_core_mfma(
    const MainArgs& ar, int band, int n, int l0, short* sA, float* blx) {
  const int rows = 32 + 2 * DIL;
  int t = threadIdx.x;
  const float* brow = ar.bands + ((size_t)band * NB + n) * LL;
  const float* ew = ar.emb_w;
  if (SECOND) {
    if (t < 34) blx[t] = brow[(l0 - 1 + t + LL) & 511];
  } else {
    if (t < rows + 2) blx[t] = brow[(l0 - DIL - 1 + t + LL) & 511];
  }
  __syncthreads();
  if (SECOND) {
    const short* srcrow = ar.y1 + ((size_t)band * NB + n) * LL * DD;
    for (int idx = t; idx < rows * 32; idx += 256) {
      int rp = idx >> 5, c4 = (idx & 31) * 4;
      int l = l0 - DIL + rp;
      short4v v = {0, 0, 0, 0};
      if (l >= 0 && l < LL) v = *(const short4v*)&srcrow[(size_t)l * DD + c4];
      *(short4v*)&sA[rp * 136 + c4] = v;
    }
  } else {
    for (int idx = t; idx < rows * DD; idx += 256) {
      int rp = idx >> 7, ci = idx & 127;
      int l = l0 - DIL + rp;
      float v = 0.f;
      if (l >= 0 && l < LL)
        v = ew[ci * 3] * blx[rp] + ew[ci * 3 + 1] * blx[rp + 1] +
            ew[ci * 3 + 2] * blx[rp + 2];
      sA[rp * 136 + ci] = f2bf(v);
    }
  }
  __syncthreads();

  int w = t >> 6, lane = t & 63;
  int r16 = lane & 15, kq = lane >> 4;
  const int m3 = (band * 2 + (SECOND ? 1 : 0)) * 3;
  const short8v* wfrv = (const short8v*)ar.wfr;
  f32x4 acc[2][2];
#pragma unroll
  for (int i = 0; i < 2; ++i)
#pragma unroll
    for (int j = 0; j < 2; ++j) acc[i][j] = (f32x4){0.f, 0.f, 0.f, 0.f};

#pragma unroll
  for (int tap = 0; tap < 3; ++tap) {
#pragma unroll
    for (int ks = 0; ks < 4; ++ks) {
      short8v a0 = *(const short8v*)&sA[(r16 + tap * DIL) * 136 + ks * 32 + kq * 8];
      short8v a1 = *(const short8v*)&sA[(16 + r16 + tap * DIL) * 136 + ks * 32 + kq * 8];
      short8v bf0 = wfrv[(((m3 + tap) * 4 + ks) * 8 + w * 2 + 0) * 64 + lane];
      short8v bf1 = wfrv[(((m3 + tap) * 4 + ks) * 8 + w * 2 + 1) * 64 + lane];
      acc[0][0] = MFMA16(a0, bf0, acc[0][0]);
      acc[0][1] = MFMA16(a0, bf1, acc[0][1]);
      acc[1][0] = MFMA16(a1, bf0, acc[1][0]);
      acc[1][1] = MFMA16(a1, bf1, acc[1][1]);
    }
  }
  int row0 = kq * 4;
  if (SECOND) {
    float* borow = ar.bo + (((size_t)band * NB + n) * LL + l0) * DD;
#pragma unroll
    for (int nt = 0; nt < 2; ++nt) {
      int dout = w * 32 + nt * 16 + r16;
      float bias = ar.b2[band][dout];
      float w0 = ew[dout * 3], w1 = ew[dout * 3 + 1], w2 = ew[dout * 3 + 2];
#pragma unroll
      for (int m = 0; m < 2; ++m)
#pragma unroll
        for (int r = 0; r < 4; ++r) {
          int pl = m * 16 + row0 + r;
          float eres = w0 * blx[pl] + w1 * blx[pl + 1] + w2 * blx[pl + 2];
          size_t o = (size_t)pl * DD + dout;
          borow[o] = borow[o] + gelu_exact(acc[m][nt][r] + bias) + eres;
        }
    }
  } else {
    short* yrow = ar.y1 + (((size_t)band * NB + n) * LL + l0) * DD;
#pragma unroll
    for (int nt = 0; nt < 2; ++nt) {
      int dout = w * 32 + nt * 16 + r16;
      float bias = ar.b1[band][dout];
#pragma unroll
      for (int m = 0; m < 2; ++m)
#pragma unroll
        for (int r = 0; r < 4; ++r)
          yrow[(size_t)(m * 16 + row0 + r) * DD + dout] =
              f2bf(gelu_exact(acc[m][nt][r] + bias));
    }
  }
}

// blocks [0,512): cheby; [512,1024): conv1
__global__ __launch_bounds__(256) void mainA_kernel(MainArgs ar) {
  __shared__ __align__(16) short sA[17408];
  __shared__ float blx[64];
  int bid = blockIdx.x;
  int b2 = bid & 511;
  int band = b2 >> 7, n = (b2 >> 4) & 7, l0 = (b2 & 15) * 32;
  if (bid < 512) {
    switch (band) {
      case 0: cheby_core_mfma<1>(ar, band, n, l0, sA, blx); break;
      case 1: cheby_core_mfma<2>(ar, band, n, l0, sA, blx); break;
      case 2: cheby_core_mfma<3>(ar, band, n, l0, sA, blx); break;
      default: cheby_core_mfma<4>(ar, band, n, l0, sA, blx); break;
    }
  } else {
    switch (band) {
      case 0: conv_core_mfma<1, false>(ar, band, n, l0, sA, blx); break;
      case 1: conv_core_mfma<2, false>(ar, band, n, l0, sA, blx); break;
      case 2: conv_core_mfma<4, false>(ar, band, n, l0, sA, blx); break;
      default: conv_core_mfma<8, false>(ar, band, n, l0, sA, blx); break;
    }
  }
}

__global__ __launch_bounds__(256) void mainB_kernel(MainArgs ar) {
  __shared__ __align__(16) short sA[6528];
  __shared__ float blx[64];
  int bid = blockIdx.x;
  int band = bid >> 7, n = (bid >> 4) & 7, l0 = (bid & 15) * 32;
  switch (band) {
    case 0: conv_core_mfma<1, true>(ar, band, n, l0, sA, blx); break;
    case 1: conv_core_mfma<2, true>(ar, band, n, l0, sA, blx); break;
    case 2: conv_core_mfma<4, true>(ar, band, n, l0, sA, blx); break;
    default: conv_core_mfma<8, true>(ar, band, n, l0, sA, blx); break;
  }
}

// head1: h[n][p][d-chunk] = pred_w @ fused + pred_b, MFMA. Block = (n, 32-d chunk).
__global__ __launch_bounds__(256) void head1_kernel(
    const float* __restrict__ bo, const short* __restrict__ pfr,
    const float* __restrict__ pred_b, float* __restrict__ h) {
  __shared__ __align__(16) short fB[32 * 520];
  int n = blockIdx.x, d0 = blockIdx.y * 32;
  int t = threadIdx.x;
  const size_t S = (size_t)NB * LL * DD;
  for (int idx = t; idx < LL * 32; idx += 256) {
    int l = idx >> 5, di = idx & 31;
    size_t base = ((size_t)n * LL + l) * DD + d0 + di;
    float v = bo[base] + bo[base + S] + bo[base + 2 * S] + bo[base + 3 * S];
    fB[di * 520 + l] = f2bf(v);
  }
  __syncthreads();
  int w = t >> 6, lane = t & 63;
  int r16 = lane & 15, kq = lane >> 4;
  int nt = w & 1, mg = (w >> 1) * 3;
  const short8v* pfrv = (const short8v*)pfr;
  f32x4 acc[3];
#pragma unroll
  for (int j = 0; j < 3; ++j) acc[j] = (f32x4){0.f, 0.f, 0.f, 0.f};
  for (int ks = 0; ks < 16; ++ks) {
    short8v bf = *(const short8v*)&fB[(nt * 16 + r16) * 520 + ks * 32 + kq * 8];
#pragma unroll
    for (int j = 0; j < 3; ++j) {
      short8v af = pfrv[(ks * 6 + mg + j) * 64 + lane];
      acc[j] = MFMA16(af, bf, acc[j]);
    }
  }
  int row0 = kq * 4;
#pragma unroll
  for (int j = 0; j < 3; ++j)
#pragma unroll
    for (int r = 0; r < 4; ++r) {
      int p = (mg + j) * 16 + row0 + r;
      h[((size_t)n * PP + p) * DD + d0 + nt * 16 + r16] = acc[j][r] + pred_b[p];
    }
}

// head2: out[n][p][q] = h[n][p][:] . proj_w[q][:] + proj_b[q]
__global__ __launch_bounds__(256) void head2_kernel(
    const float* __restrict__ h, const float* __restrict__ proj_w,
    const float* __restrict__ proj_b, float* __restrict__ out) {
  int n = blockIdx.x, t = threadIdx.x;
  for (int i = t; i < PP * QQ; i += 256) {
    int p = i / QQ, q = i - p * QQ;
    const float* hr = h + ((size_t)n * PP + p) * DD;
    const float* pw = proj_w + (size_t)q * DD;
    float s = proj_b[q];
    for (int d = 0; d < DD; ++d) s += hr[d] * pw[d];
    out[(size_t)n * (PP * QQ) + i] = s;
  }
}

extern "C" void kernel_launch(void* const* d_in, const int* in_sizes, int n_in,
                              void* d_out, int out_size, void* d_ws, size_t ws_size,
                              hipStream_t stream) {
  const float* emb_w = (const float*)d_in[1];
  const float* proj_w = (const float*)d_in[22];
  const float* proj_b = (const float*)d_in[23];
  const float* pred_w = (const float*)d_in[24];
  const float* pred_b = (const float*)d_in[25];
  float* ws = (float*)d_ws;
  float* bands = ws + WS_BANDS;
  float* bo = ws + WS_BO;
  short* y1 = (short*)(ws + WS_Y1);
  float* h = ws + WS_H;
  short* cfr = (short*)(ws + WS_CFR);
  short* wfr = (short*)(ws + WS_WFR);
  short* pfr = (short*)(ws + WS_PFR);
  float* b0 = ws + WS_B0;
  float* out = (float*)d_out;

  PrepArgs pa;
  pa.x_enc = (const float*)d_in[0];
  for (int i = 0; i < 4; ++i) {
    pa.cheb[i] = (const float*)d_in[2 + 5 * i];
    pa.w1[i] = (const float*)d_in[3 + 5 * i];
    pa.w2[i] = (const float*)d_in[5 + 5 * i];
  }
  pa.pred_w = pred_w;
  pa.bands = bands; pa.cfr = cfr; pa.wfr = wfr; pa.pfr = pfr; pa.b0 = b0;

  MainArgs ma;
  ma.emb_w = emb_w; ma.bands = bands; ma.cfr = cfr; ma.wfr = wfr;
  for (int i = 0; i < 4; ++i) {
    ma.b1[i] = (const float*)d_in[4 + 5 * i];
    ma.b2[i] = (const float*)d_in[6 + 5 * i];
  }
  ma.b0 = b0; ma.y1 = y1; ma.bo = bo;

  prep_kernel<<<160, 256, 0, stream>>>(pa);
  mainA_kernel<<<1024, 256, 0, stream>>>(ma);
  mainB_kernel<<<512, 256, 0, stream>>>(ma);
  head1_kernel<<<dim3(NB, 4), 256, 0, stream>>>(bo, pfr, pred_b, h);
  head2_kernel<<<NB, 256, 0, stream>>>(h, proj_w, proj_b, out);
}